// Round 1
// baseline (1840.164 us; speedup 1.0000x reference)
//
#include <hip/hip_runtime.h>
#include <hip/hip_bf16.h>
#include <stdint.h>

// Problem constants
#define Bz 64
#define Lz 2048
#define Hz 1024
#define Uz 1024
#define Vz 32000
#define Ez 256

typedef __attribute__((ext_vector_type(8))) short bf16x8;
typedef __attribute__((ext_vector_type(4))) float f32x4;

__device__ __forceinline__ unsigned short f2bf(float f) {
    unsigned int u = __float_as_uint(f);
    u += 0x7fffu + ((u >> 16) & 1u);   // round-to-nearest-even
    return (unsigned short)(u >> 16);
}

__device__ __forceinline__ float tanh_fast(float x) {
    float e = __expf(2.0f * x);
    return (e - 1.0f) * __builtin_amdgcn_rcpf(e + 1.0f);
}

__device__ __forceinline__ void async_cp16(const void* g, void* l) {
    __builtin_amdgcn_global_load_lds(
        (const __attribute__((address_space(1))) void*)g,
        (__attribute__((address_space(3))) void*)l, 16, 0, 0);
}

// ---------------------------------------------------------------------------
// K0: pack w1 (H x U fp32, row-major [k][n]) into bf16 MFMA-B slab order:
//     w1p[slab][n][kk], slab = k/32, kk = k%32. A 32-K slab for an n-range is
//     then a single linear region -> global_load_lds-friendly.
__global__ void pack_w1_kernel(const float* __restrict__ w1,
                               unsigned short* __restrict__ w1p) {
    int g = blockIdx.x * 256 + threadIdx.x;   // 0 .. 1048575
    int slab = g >> 15;
    int rem  = g & 32767;
    int n    = rem >> 5;
    int kk   = rem & 31;
    w1p[g] = f2bf(w1[(size_t)((slab << 5) + kk) * Uz + n]);
}

// ---------------------------------------------------------------------------
// K1: hid = hidden @ w2 (no bias; b2 added in score epilogue). K-split x4 with
// atomicAdd into zeroed ws buffer. grid (4 ktiles, 4 coltiles, 8 rowtiles).
__global__ void hid_kernel(const float* __restrict__ hidden,
                           const float* __restrict__ w2,
                           float* __restrict__ hid) {
    __shared__ float lh[8 * 256];
    int t   = threadIdx.x;
    int k0  = blockIdx.x * 256;
    int col = blockIdx.y * 256 + t;
    int r0  = blockIdx.z * 8;
#pragma unroll
    for (int i = 0; i < 8; ++i) {
        int idx = i * 256 + t;
        lh[idx] = hidden[(r0 + (idx >> 8)) * Uz + k0 + (idx & 255)];
    }
    __syncthreads();
    float acc[8];
#pragma unroll
    for (int r = 0; r < 8; ++r) acc[r] = 0.f;
    for (int kk = 0; kk < 256; ++kk) {
        float w = w2[(size_t)(k0 + kk) * Uz + col];
#pragma unroll
        for (int r = 0; r < 8; ++r) acc[r] = fmaf(lh[r * 256 + kk], w, acc[r]);
    }
#pragma unroll
    for (int r = 0; r < 8; ++r) atomicAdd(&hid[(r0 + r) * Uz + col], acc[r]);
}

// ---------------------------------------------------------------------------
// K2: fused score kernel. scores[b,l] = sum_n tanh(enc[row,:]@w1[:,n] + b1[n]
//     + b2[n] + hid[b,n]) * vw[n], accumulated via atomicAdd over 2 N-halves.
// BM=64, BN=512, BK=32, 256 threads (4 waves), wave tile 64x128,
// mfma_f32_16x16x32_bf16, 4x8 accum frags (128 AGPR/lane).
__global__ __launch_bounds__(256, 2)
void score_kernel(const float* __restrict__ enc,
                  const unsigned short* __restrict__ w1p,
                  const float* __restrict__ b1, const float* __restrict__ b2,
                  const float* __restrict__ hid, const float* __restrict__ vw,
                  float* __restrict__ scores) {
    __shared__ __align__(16) float lA[64 * 32];            // fp32 A tile, chunk-swizzled
    __shared__ __align__(16) unsigned short lB[512 * 32];  // bf16 B tile [n][kk]

    const int t    = threadIdx.x;
    const int lane = t & 63;
    const int wave = t >> 6;
    const int ln   = lane & 15;
    const int q    = lane >> 4;
    const int n0   = blockIdx.x * 512;       // 0 or 512
    const int m0   = blockIdx.y * 64;        // global row tile (row = b*L + l)
    const int bidx = m0 >> 11;               // m0 / L

    f32x4 acc[4][8];
    const f32x4 zero = {0.f, 0.f, 0.f, 0.f};
#pragma unroll
    for (int ms = 0; ms < 4; ++ms)
#pragma unroll
        for (int s = 0; s < 8; ++s) acc[ms][s] = zero;

    const char* w1base = ((const char*)w1p) + n0 * 64;

    for (int kt = 0; kt < 32; ++kt) {
        __syncthreads();
        // Stage B: linear 32KB copy of slab kt, n-range [n0, n0+512)
        const char* bsrc = w1base + kt * 65536;
#pragma unroll
        for (int i = 0; i < 8; ++i) {
            int cb = i * 256 + t;
            async_cp16(bsrc + cb * 16, ((char*)lB) + cb * 16);
        }
        // Stage A: 64 rows x 32 fp32, XOR-swizzled 16B chunks for conflict-free
        // frag reads. Physical chunk P holds logical chunk (P%8) ^ (m&7) of row m.
#pragma unroll
        for (int i = 0; i < 2; ++i) {
            int P = i * 256 + t;
            int m = P >> 3, p = P & 7;
            int c = p ^ (m & 7);
            async_cp16(enc + (size_t)(m0 + m) * Hz + kt * 32 + c * 4,
                       ((char*)lA) + P * 16);
        }
        __syncthreads();

        // Build A frags: A[m = ms*16 + ln][k = q*8 + j]
        bf16x8 afr[4];
#pragma unroll
        for (int ms = 0; ms < 4; ++ms) {
            int m = ms * 16 + ln;
            int c0 = (2 * q) ^ (m & 7);
            int c1 = (2 * q + 1) ^ (m & 7);
            float4 x0 = *(const float4*)&lA[m * 32 + c0 * 4];
            float4 x1 = *(const float4*)&lA[m * 32 + c1 * 4];
            union { bf16x8 v; __hip_bfloat162 h[4]; } u;
            u.h[0] = __float22bfloat162_rn(make_float2(x0.x, x0.y));
            u.h[1] = __float22bfloat162_rn(make_float2(x0.z, x0.w));
            u.h[2] = __float22bfloat162_rn(make_float2(x1.x, x1.y));
            u.h[3] = __float22bfloat162_rn(make_float2(x1.z, x1.w));
            afr[ms] = u.v;
        }
#pragma unroll
        for (int s = 0; s < 8; ++s) {
            int nl = wave * 128 + s * 16 + ln;     // B[k = q*8 + j][n = nl]
            bf16x8 bfr = *(const bf16x8*)&lB[nl * 32 + q * 8];
#pragma unroll
            for (int ms = 0; ms < 4; ++ms)
                acc[ms][s] = __builtin_amdgcn_mfma_f32_16x16x32_bf16(
                    afr[ms], bfr, acc[ms][s], 0, 0, 0);
        }
    }

    // Epilogue: tanh + dot with v_w, reduce over n (lanes ln=0..15), atomicAdd.
    const float* hidb = hid + bidx * Uz;
    float psum[4][4];
#pragma unroll
    for (int ms = 0; ms < 4; ++ms)
#pragma unroll
        for (int r = 0; r < 4; ++r) psum[ms][r] = 0.f;
#pragma unroll
    for (int s = 0; s < 8; ++s) {
        int n = n0 + wave * 128 + s * 16 + ln;
        float bias = b1[n] + b2[n] + hidb[n];
        float vwn = vw[n];
#pragma unroll
        for (int ms = 0; ms < 4; ++ms)
#pragma unroll
            for (int r = 0; r < 4; ++r)
                psum[ms][r] += tanh_fast(acc[ms][s][r] + bias) * vwn;
    }
#pragma unroll
    for (int ms = 0; ms < 4; ++ms)
#pragma unroll
        for (int r = 0; r < 4; ++r) {
            float v = psum[ms][r];
            v += __shfl_xor(v, 1);
            v += __shfl_xor(v, 2);
            v += __shfl_xor(v, 4);
            v += __shfl_xor(v, 8);
            if (ln == 0) atomicAdd(&scores[m0 + ms * 16 + q * 4 + r], v);
        }
}

// ---------------------------------------------------------------------------
// K3: softmax over L per batch row; writes attention_weights to d_out.
__global__ void softmax_kernel(const float* __restrict__ scores,
                               float* __restrict__ attn) {
    int b = blockIdx.x, t = threadIdx.x;
    __shared__ float sm[4], ss[4];
    float v[8];
    float mx = -1e30f;
#pragma unroll
    for (int i = 0; i < 8; ++i) {
        v[i] = scores[b * Lz + i * 256 + t];
        mx = fmaxf(mx, v[i]);
    }
    for (int o = 1; o < 64; o <<= 1) mx = fmaxf(mx, __shfl_xor(mx, o));
    if ((t & 63) == 0) sm[t >> 6] = mx;
    __syncthreads();
    mx = fmaxf(fmaxf(sm[0], sm[1]), fmaxf(sm[2], sm[3]));
    float sum = 0.f;
#pragma unroll
    for (int i = 0; i < 8; ++i) { v[i] = __expf(v[i] - mx); sum += v[i]; }
    for (int o = 1; o < 64; o <<= 1) sum += __shfl_xor(sum, o);
    if ((t & 63) == 0) ss[t >> 6] = sum;
    __syncthreads();
    sum = ss[0] + ss[1] + ss[2] + ss[3];
    float inv = 1.0f / sum;
#pragma unroll
    for (int i = 0; i < 8; ++i) attn[b * Lz + i * 256 + t] = v[i] * inv;
}

// ---------------------------------------------------------------------------
// K4: context[b,h] = sum_l attn[b,l] * enc[b,l,h]. Pure-BW second enc pass.
// grid (4 h-chunks, 4 l-chunks, 64 b), atomicAdd partials into zeroed ctx.
__global__ void context_kernel(const float* __restrict__ enc,
                               const float* __restrict__ attn,
                               float* __restrict__ ctx) {
    int h  = blockIdx.x * 256 + threadIdx.x;
    int l0 = blockIdx.y * 512;
    int b  = blockIdx.z;
    const float* ep = enc + ((size_t)b * Lz + l0) * Hz + h;
    const float* ap = attn + b * Lz + l0;
    float acc = 0.f;
#pragma unroll 8
    for (int l = 0; l < 512; ++l) acc = fmaf(ap[l], ep[(size_t)l * Hz], acc);
    atomicAdd(&ctx[b * Uz + h], acc);
}

// ---------------------------------------------------------------------------
// K5: GRU with h0 = 0 => state = (1 - sigmoid(zi_z)) * tanh(zi_h). The r-gate
// and gru_rk are dead. 2 batch rows per block to reuse gru_k loads.
__global__ void gru_kernel(const int* __restrict__ x,
                           const float* __restrict__ emb,
                           const float* __restrict__ ctx,
                           const float* __restrict__ gk,
                           const float* __restrict__ gb,
                           float* __restrict__ state) {
    int u  = blockIdx.y * 256 + threadIdx.x;
    int b0 = blockIdx.x * 2;
    float az0 = 0, az1 = 0, ah0 = 0, ah1 = 0;
    const float* c0 = ctx + b0 * Uz;
    const float* c1 = c0 + Uz;
    const float* e0 = emb + (size_t)x[b0] * Ez;
    const float* e1 = emb + (size_t)x[b0 + 1] * Ez;
    for (int k = 0; k < Hz; ++k) {
        float wz = gk[(size_t)k * 3072 + u];
        float wh = gk[(size_t)k * 3072 + 2048 + u];
        float x0 = c0[k], x1 = c1[k];
        az0 = fmaf(x0, wz, az0); ah0 = fmaf(x0, wh, ah0);
        az1 = fmaf(x1, wz, az1); ah1 = fmaf(x1, wh, ah1);
    }
    for (int k = 0; k < Ez; ++k) {
        float wz = gk[(size_t)(Hz + k) * 3072 + u];
        float wh = gk[(size_t)(Hz + k) * 3072 + 2048 + u];
        float x0 = e0[k], x1 = e1[k];
        az0 = fmaf(x0, wz, az0); ah0 = fmaf(x0, wh, ah0);
        az1 = fmaf(x1, wz, az1); ah1 = fmaf(x1, wh, ah1);
    }
    float gz = gb[u], gh = gb[2048 + u];
    float z0 = __builtin_amdgcn_rcpf(1.f + __expf(-(az0 + gz)));
    float z1 = __builtin_amdgcn_rcpf(1.f + __expf(-(az1 + gz)));
    state[b0 * Uz + u]       = (1.f - z0) * tanh_fast(ah0 + gh);
    state[(b0 + 1) * Uz + u] = (1.f - z1) * tanh_fast(ah1 + gh);
}

// ---------------------------------------------------------------------------
// K6: logits = state @ out_w + out_b. 500 blocks x 256 thr = 64 cols x 4
// row-quads; state staged per 128-K chunk in LDS (broadcast reads).
__global__ __launch_bounds__(256)
void logits_kernel(const float* __restrict__ state,
                   const float* __restrict__ ow, const float* __restrict__ ob,
                   float* __restrict__ out) {
    __shared__ float ls[64 * 128];
    int t   = threadIdx.x;
    int col = blockIdx.x * 64 + (t & 63);
    int rq  = t >> 6;
    float acc[16];
#pragma unroll
    for (int r = 0; r < 16; ++r) acc[r] = 0.f;
    for (int kc = 0; kc < 8; ++kc) {
        __syncthreads();
#pragma unroll
        for (int i = 0; i < 32; ++i) {
            int idx = i * 256 + t;
            ls[idx] = state[(idx >> 7) * Uz + kc * 128 + (idx & 127)];
        }
        __syncthreads();
        const float* base = ls + rq * 16 * 128;
        for (int kk = 0; kk < 128; ++kk) {
            float w = ow[(size_t)(kc * 128 + kk) * Vz + col];
#pragma unroll
            for (int r = 0; r < 16; ++r)
                acc[r] = fmaf(base[r * 128 + kk], w, acc[r]);
        }
    }
    float bb = ob[col];
#pragma unroll
    for (int r = 0; r < 16; ++r)
        out[(size_t)(rq * 16 + r) * Vz + col] = acc[r] + bb;
}

// ---------------------------------------------------------------------------
extern "C" void kernel_launch(void* const* d_in, const int* in_sizes, int n_in,
                              void* d_out, int out_size, void* d_ws, size_t ws_size,
                              hipStream_t stream) {
    const int*   x      = (const int*)d_in[0];
    const float* hidden = (const float*)d_in[1];
    const float* enc    = (const float*)d_in[2];
    const float* emb    = (const float*)d_in[3];
    const float* w1     = (const float*)d_in[4];
    const float* b1     = (const float*)d_in[5];
    const float* w2     = (const float*)d_in[6];
    const float* b2     = (const float*)d_in[7];
    const float* vw     = (const float*)d_in[8];
    // d_in[9] = v_b: softmax is shift-invariant, score is not an output -> unused
    const float* gk     = (const float*)d_in[10];
    // d_in[11] = gru_rk: dead (h0 == 0)
    const float* gb     = (const float*)d_in[12];
    const float* ow     = (const float*)d_in[13];
    const float* ob     = (const float*)d_in[14];

    float* out    = (float*)d_out;
    float* logits = out;                        // 64*32000
    float* state  = out + (size_t)Bz * Vz;      // 64*1024
    float* attn   = state + (size_t)Bz * Uz;    // 64*2048

    char* ws = (char*)d_ws;
    float* scores = (float*)ws;                          // 512 KB
    float* ctx    = (float*)(ws + 524288);               // 256 KB
    float* hid    = (float*)(ws + 786432);               // 256 KB
    unsigned short* w1p = (unsigned short*)(ws + 1048576); // 2 MB bf16-packed w1

    // Zero the atomic-accumulated buffers (scores, ctx, hid = first 1 MB).
    hipMemsetAsync(d_ws, 0, 1048576, stream);

    pack_w1_kernel<<<4096, 256, 0, stream>>>(w1, w1p);
    hid_kernel<<<dim3(4, 4, 8), 256, 0, stream>>>(hidden, w2, hid);
    score_kernel<<<dim3(2, Bz * Lz / 64), 256, 0, stream>>>(enc, w1p, b1, b2,
                                                            hid, vw, scores);
    softmax_kernel<<<Bz, 256, 0, stream>>>(scores, attn);
    context_kernel<<<dim3(4, 4, Bz), 256, 0, stream>>>(enc, attn, ctx);
    gru_kernel<<<dim3(Bz / 2, 4), 256, 0, stream>>>(x, emb, ctx, gk, gb, state);
    logits_kernel<<<Vz / 64, 256, 0, stream>>>(state, ow, ob, logits);
}

// Round 2
// 1455.315 us; speedup vs baseline: 1.2644x; 1.2644x over previous
//
#include <hip/hip_runtime.h>
#include <hip/hip_bf16.h>
#include <stdint.h>

// Problem constants
#define Bz 64
#define Lz 2048
#define Hz 1024
#define Uz 1024
#define Vz 32000
#define Ez 256

typedef __attribute__((ext_vector_type(8))) short bf16x8;
typedef __attribute__((ext_vector_type(4))) float f32x4;

__device__ __forceinline__ unsigned short f2bf(float f) {
    unsigned int u = __float_as_uint(f);
    u += 0x7fffu + ((u >> 16) & 1u);   // round-to-nearest-even
    return (unsigned short)(u >> 16);
}

__device__ __forceinline__ float tanh_fast(float x) {
    float e = __expf(2.0f * x);
    return (e - 1.0f) * __builtin_amdgcn_rcpf(e + 1.0f);
}

__device__ __forceinline__ void async_cp16(const void* g, void* l) {
    __builtin_amdgcn_global_load_lds(
        (const __attribute__((address_space(1))) void*)g,
        (__attribute__((address_space(3))) void*)l, 16, 0, 0);
}

// ---------------------------------------------------------------------------
// K0: pack w1 (H x U fp32, row-major [k][n]) into bf16 MFMA-B slab order:
//     w1p[slab][n][kk], slab = k/32, kk = k%32. LDS-tiled so global reads are
//     coalesced (prev version read at stride 4KB per lane -> uncoalesced).
__global__ void pack_w1_kernel(const float* __restrict__ w1,
                               unsigned short* __restrict__ w1p) {
    __shared__ float tile[32][257];
    int nb = blockIdx.x;   // n-block of 256
    int kb = blockIdx.y;   // k-slab of 32
    int t  = threadIdx.x;
#pragma unroll
    for (int i = 0; i < 32; ++i)
        tile[i][t] = w1[(size_t)(kb * 32 + i) * Uz + nb * 256 + t];
    __syncthreads();
    union { uint4 v[4]; unsigned short s[32]; } u;
#pragma unroll
    for (int kk = 0; kk < 32; ++kk) u.s[kk] = f2bf(tile[kk][t]);
    uint4* d4 = (uint4*)(w1p + (size_t)kb * 32768 + (size_t)(nb * 256 + t) * 32);
#pragma unroll
    for (int j = 0; j < 4; ++j) d4[j] = u.v[j];
}

// ---------------------------------------------------------------------------
// K1a: transpose hidden (64 x 1024) -> hiddenT (1024 x 64) for scalar-broadcast
// GEMM. grid 16 blocks of 256.
__global__ void transpose_hidden_kernel(const float* __restrict__ hidden,
                                        float* __restrict__ hT) {
    __shared__ float tile[64][65];
    int cb = blockIdx.x;
    int t  = threadIdx.x;
    int tc = t & 63, tr = t >> 6;
#pragma unroll
    for (int i = 0; i < 16; ++i) {
        int r = i * 4 + tr;
        tile[r][tc] = hidden[(size_t)r * Uz + cb * 64 + tc];
    }
    __syncthreads();
#pragma unroll
    for (int i = 0; i < 16; ++i) {
        int k = i * 4 + tr;
        hT[(size_t)(cb * 64 + k) * 64 + tc] = tile[tc][k];
    }
}

// K1b: hid = hidden @ w2 via scalar-broadcast: stateT rows are wave-uniform ->
// s_load; w2 reads coalesced; 64 row-accumulators in VGPRs. K-split x16 with
// atomicAdd into zeroed hid. grid (4 n-blocks, 16 k-splits).
__global__ __launch_bounds__(256)
void hid_gemm_kernel(const float* __restrict__ hT, const float* __restrict__ w2,
                     float* __restrict__ hid) {
    int col = blockIdx.x * 256 + threadIdx.x;
    int k0  = blockIdx.y * 64;
    float acc[64];
#pragma unroll
    for (int r = 0; r < 64; ++r) acc[r] = 0.f;
#pragma unroll 4
    for (int k = 0; k < 64; ++k) {
        float w = w2[(size_t)(k0 + k) * Uz + col];
        const float* srow = hT + (size_t)(k0 + k) * 64;
#pragma unroll
        for (int r = 0; r < 64; ++r) acc[r] = fmaf(srow[r], w, acc[r]);
    }
#pragma unroll
    for (int r = 0; r < 64; ++r) atomicAdd(&hid[(size_t)r * Uz + col], acc[r]);
}

// ---------------------------------------------------------------------------
// K2: fused score kernel. scores[b,l] = sum_n tanh(enc[row,:]@w1[:,n] + b1[n]
//     + b2[n] + hid[b,n]) * vw[n], accumulated via atomicAdd over 2 N-halves.
// BM=64, BN=512, BK=32, 256 threads (4 waves), wave tile 64x128,
// mfma_f32_16x16x32_bf16, 4x8 accum frags (128 AGPR/lane).
__global__ __launch_bounds__(256, 2)
void score_kernel(const float* __restrict__ enc,
                  const unsigned short* __restrict__ w1p,
                  const float* __restrict__ b1, const float* __restrict__ b2,
                  const float* __restrict__ hid, const float* __restrict__ vw,
                  float* __restrict__ scores) {
    __shared__ __align__(16) float lA[64 * 32];            // fp32 A tile, chunk-swizzled
    __shared__ __align__(16) unsigned short lB[512 * 32];  // bf16 B tile [n][kk]

    const int t    = threadIdx.x;
    const int lane = t & 63;
    const int wave = t >> 6;
    const int ln   = lane & 15;
    const int q    = lane >> 4;
    const int n0   = blockIdx.x * 512;       // 0 or 512
    const int m0   = blockIdx.y * 64;        // global row tile (row = b*L + l)
    const int bidx = m0 >> 11;               // m0 / L

    f32x4 acc[4][8];
    const f32x4 zero = {0.f, 0.f, 0.f, 0.f};
#pragma unroll
    for (int ms = 0; ms < 4; ++ms)
#pragma unroll
        for (int s = 0; s < 8; ++s) acc[ms][s] = zero;

    const char* w1base = ((const char*)w1p) + n0 * 64;

    for (int kt = 0; kt < 32; ++kt) {
        __syncthreads();
        // Stage B: linear 32KB copy of slab kt, n-range [n0, n0+512)
        const char* bsrc = w1base + kt * 65536;
#pragma unroll
        for (int i = 0; i < 8; ++i) {
            int cb = i * 256 + t;
            async_cp16(bsrc + cb * 16, ((char*)lB) + cb * 16);
        }
        // Stage A: 64 rows x 32 fp32, XOR-swizzled 16B chunks for conflict-free
        // frag reads. Physical chunk P holds logical chunk (P%8) ^ (m&7) of row m.
#pragma unroll
        for (int i = 0; i < 2; ++i) {
            int P = i * 256 + t;
            int m = P >> 3, p = P & 7;
            int c = p ^ (m & 7);
            async_cp16(enc + (size_t)(m0 + m) * Hz + kt * 32 + c * 4,
                       ((char*)lA) + P * 16);
        }
        __syncthreads();

        // Build A frags: A[m = ms*16 + ln][k = q*8 + j]
        bf16x8 afr[4];
#pragma unroll
        for (int ms = 0; ms < 4; ++ms) {
            int m = ms * 16 + ln;
            int c0 = (2 * q) ^ (m & 7);
            int c1 = (2 * q + 1) ^ (m & 7);
            float4 x0 = *(const float4*)&lA[m * 32 + c0 * 4];
            float4 x1 = *(const float4*)&lA[m * 32 + c1 * 4];
            union { bf16x8 v; __hip_bfloat162 h[4]; } u;
            u.h[0] = __float22bfloat162_rn(make_float2(x0.x, x0.y));
            u.h[1] = __float22bfloat162_rn(make_float2(x0.z, x0.w));
            u.h[2] = __float22bfloat162_rn(make_float2(x1.x, x1.y));
            u.h[3] = __float22bfloat162_rn(make_float2(x1.z, x1.w));
            afr[ms] = u.v;
        }
#pragma unroll
        for (int s = 0; s < 8; ++s) {
            int nl = wave * 128 + s * 16 + ln;     // B[k = q*8 + j][n = nl]
            bf16x8 bfr = *(const bf16x8*)&lB[nl * 32 + q * 8];
#pragma unroll
            for (int ms = 0; ms < 4; ++ms)
                acc[ms][s] = __builtin_amdgcn_mfma_f32_16x16x32_bf16(
                    afr[ms], bfr, acc[ms][s], 0, 0, 0);
        }
    }

    // Epilogue: tanh + dot with v_w, reduce over n (lanes ln=0..15), atomicAdd.
    const float* hidb = hid + bidx * Uz;
    float psum[4][4];
#pragma unroll
    for (int ms = 0; ms < 4; ++ms)
#pragma unroll
        for (int r = 0; r < 4; ++r) psum[ms][r] = 0.f;
#pragma unroll
    for (int s = 0; s < 8; ++s) {
        int n = n0 + wave * 128 + s * 16 + ln;
        float bias = b1[n] + b2[n] + hidb[n];
        float vwn = vw[n];
#pragma unroll
        for (int ms = 0; ms < 4; ++ms)
#pragma unroll
            for (int r = 0; r < 4; ++r)
                psum[ms][r] += tanh_fast(acc[ms][s][r] + bias) * vwn;
    }
#pragma unroll
    for (int ms = 0; ms < 4; ++ms)
#pragma unroll
        for (int r = 0; r < 4; ++r) {
            float v = psum[ms][r];
            v += __shfl_xor(v, 1);
            v += __shfl_xor(v, 2);
            v += __shfl_xor(v, 4);
            v += __shfl_xor(v, 8);
            if (ln == 0) atomicAdd(&scores[m0 + ms * 16 + q * 4 + r], v);
        }
}

// ---------------------------------------------------------------------------
// K3: softmax over L per batch row; writes attention_weights to d_out.
__global__ void softmax_kernel(const float* __restrict__ scores,
                               float* __restrict__ attn) {
    int b = blockIdx.x, t = threadIdx.x;
    __shared__ float sm[4], ss[4];
    float v[8];
    float mx = -1e30f;
#pragma unroll
    for (int i = 0; i < 8; ++i) {
        v[i] = scores[b * Lz + i * 256 + t];
        mx = fmaxf(mx, v[i]);
    }
    for (int o = 1; o < 64; o <<= 1) mx = fmaxf(mx, __shfl_xor(mx, o));
    if ((t & 63) == 0) sm[t >> 6] = mx;
    __syncthreads();
    mx = fmaxf(fmaxf(sm[0], sm[1]), fmaxf(sm[2], sm[3]));
    float sum = 0.f;
#pragma unroll
    for (int i = 0; i < 8; ++i) { v[i] = __expf(v[i] - mx); sum += v[i]; }
    for (int o = 1; o < 64; o <<= 1) sum += __shfl_xor(sum, o);
    if ((t & 63) == 0) ss[t >> 6] = sum;
    __syncthreads();
    sum = ss[0] + ss[1] + ss[2] + ss[3];
    float inv = 1.0f / sum;
#pragma unroll
    for (int i = 0; i < 8; ++i) attn[b * Lz + i * 256 + t] = v[i] * inv;
}

// ---------------------------------------------------------------------------
// K4: context[b,h] = sum_l attn[b,l] * enc[b,l,h]. Pure-BW second enc pass.
// grid (4 h-chunks, 4 l-chunks, 64 b), atomicAdd partials into zeroed ctx.
__global__ void context_kernel(const float* __restrict__ enc,
                               const float* __restrict__ attn,
                               float* __restrict__ ctx) {
    int h  = blockIdx.x * 256 + threadIdx.x;
    int l0 = blockIdx.y * 512;
    int b  = blockIdx.z;
    const float* ep = enc + ((size_t)b * Lz + l0) * Hz + h;
    const float* ap = attn + b * Lz + l0;
    float acc = 0.f;
#pragma unroll 8
    for (int l = 0; l < 512; ++l) acc = fmaf(ap[l], ep[(size_t)l * Hz], acc);
    atomicAdd(&ctx[b * Uz + h], acc);
}

// ---------------------------------------------------------------------------
// K5: GRU with h0 = 0 => state = (1 - sigmoid(zi_z)) * tanh(zi_h). The r-gate
// and gru_rk are dead. 2 batch rows per block to reuse gru_k loads.
// Also writes stateT (1024 x 64) for the scalar-broadcast logits GEMM.
__global__ void gru_kernel(const int* __restrict__ x,
                           const float* __restrict__ emb,
                           const float* __restrict__ ctx,
                           const float* __restrict__ gk,
                           const float* __restrict__ gb,
                           float* __restrict__ state,
                           float* __restrict__ stateT) {
    int u  = blockIdx.y * 256 + threadIdx.x;
    int b0 = blockIdx.x * 2;
    float az0 = 0, az1 = 0, ah0 = 0, ah1 = 0;
    const float* c0 = ctx + b0 * Uz;
    const float* c1 = c0 + Uz;
    const float* e0 = emb + (size_t)x[b0] * Ez;
    const float* e1 = emb + (size_t)x[b0 + 1] * Ez;
    for (int k = 0; k < Hz; ++k) {
        float wz = gk[(size_t)k * 3072 + u];
        float wh = gk[(size_t)k * 3072 + 2048 + u];
        float x0 = c0[k], x1 = c1[k];
        az0 = fmaf(x0, wz, az0); ah0 = fmaf(x0, wh, ah0);
        az1 = fmaf(x1, wz, az1); ah1 = fmaf(x1, wh, ah1);
    }
    for (int k = 0; k < Ez; ++k) {
        float wz = gk[(size_t)(Hz + k) * 3072 + u];
        float wh = gk[(size_t)(Hz + k) * 3072 + 2048 + u];
        float x0 = e0[k], x1 = e1[k];
        az0 = fmaf(x0, wz, az0); ah0 = fmaf(x0, wh, ah0);
        az1 = fmaf(x1, wz, az1); ah1 = fmaf(x1, wh, ah1);
    }
    float gz = gb[u], gh = gb[2048 + u];
    float z0 = __builtin_amdgcn_rcpf(1.f + __expf(-(az0 + gz)));
    float z1 = __builtin_amdgcn_rcpf(1.f + __expf(-(az1 + gz)));
    float s0 = (1.f - z0) * tanh_fast(ah0 + gh);
    float s1 = (1.f - z1) * tanh_fast(ah1 + gh);
    state[b0 * Uz + u]       = s0;
    state[(b0 + 1) * Uz + u] = s1;
    stateT[(size_t)u * 64 + b0]     = s0;
    stateT[(size_t)u * 64 + b0 + 1] = s1;
}

// ---------------------------------------------------------------------------
// K6: logits = state @ out_w + out_b via scalar-broadcast skinny GEMM.
// stateT rows (all 64 batch rows for a fixed k) are wave-uniform -> scalar
// s_load (SMEM pipe, no LDS); out_w read coalesced once; 64 accumulators in
// VGPRs. K-split x4, atomicAdd into zeroed logits. grid (125, 4) x 256 thr.
__global__ __launch_bounds__(256)
void logits_kernel(const float* __restrict__ stateT,
                   const float* __restrict__ ow, const float* __restrict__ ob,
                   float* __restrict__ out) {
    int col = blockIdx.x * 256 + threadIdx.x;
    int k0  = blockIdx.y * 256;
    float acc[64];
#pragma unroll
    for (int r = 0; r < 64; ++r) acc[r] = 0.f;
#pragma unroll 4
    for (int k = 0; k < 256; ++k) {
        float w = ow[(size_t)(k0 + k) * Vz + col];
        const float* srow = stateT + (size_t)(k0 + k) * 64;
#pragma unroll
        for (int r = 0; r < 64; ++r) acc[r] = fmaf(srow[r], w, acc[r]);
    }
    float bb = (blockIdx.y == 0) ? ob[col] : 0.f;
#pragma unroll
    for (int r = 0; r < 64; ++r)
        atomicAdd(&out[(size_t)r * Vz + col], acc[r] + bb);
}

// ---------------------------------------------------------------------------
extern "C" void kernel_launch(void* const* d_in, const int* in_sizes, int n_in,
                              void* d_out, int out_size, void* d_ws, size_t ws_size,
                              hipStream_t stream) {
    const int*   x      = (const int*)d_in[0];
    const float* hidden = (const float*)d_in[1];
    const float* enc    = (const float*)d_in[2];
    const float* emb    = (const float*)d_in[3];
    const float* w1     = (const float*)d_in[4];
    const float* b1     = (const float*)d_in[5];
    const float* w2     = (const float*)d_in[6];
    const float* b2     = (const float*)d_in[7];
    const float* vw     = (const float*)d_in[8];
    // d_in[9] = v_b: softmax is shift-invariant, score is not an output -> unused
    const float* gk     = (const float*)d_in[10];
    // d_in[11] = gru_rk: dead (h0 == 0)
    const float* gb     = (const float*)d_in[12];
    const float* ow     = (const float*)d_in[13];
    const float* ob     = (const float*)d_in[14];

    float* out    = (float*)d_out;
    float* logits = out;                        // 64*32000
    float* state  = out + (size_t)Bz * Vz;      // 64*1024
    float* attn   = state + (size_t)Bz * Uz;    // 64*2048

    char* ws = (char*)d_ws;
    float* scores = (float*)ws;                          // 512 KB
    float* ctx    = (float*)(ws + 524288);               // 256 KB
    float* hid    = (float*)(ws + 786432);               // 256 KB
    unsigned short* w1p = (unsigned short*)(ws + 1048576); // 2 MB bf16-packed w1
    float* stateT = (float*)(ws + 3145728);              // 256 KB
    float* hT     = (float*)(ws + 3407872);              // 256 KB

    // Zero the atomic-accumulated buffers (scores, ctx, hid = first 1 MB) and
    // the logits region of d_out (atomicAdd target).
    hipMemsetAsync(d_ws, 0, 1048576, stream);
    hipMemsetAsync(d_out, 0, (size_t)Bz * Vz * sizeof(float), stream);

    pack_w1_kernel<<<dim3(4, 32), 256, 0, stream>>>(w1, w1p);
    transpose_hidden_kernel<<<16, 256, 0, stream>>>(hidden, hT);
    hid_gemm_kernel<<<dim3(4, 16), 256, 0, stream>>>(hT, w2, hid);
    score_kernel<<<dim3(2, Bz * Lz / 64), 256, 0, stream>>>(enc, w1p, b1, b2,
                                                            hid, vw, scores);
    softmax_kernel<<<Bz, 256, 0, stream>>>(scores, attn);
    context_kernel<<<dim3(4, 4, Bz), 256, 0, stream>>>(enc, attn, ctx);
    gru_kernel<<<dim3(Bz / 2, 4), 256, 0, stream>>>(x, emb, ctx, gk, gb, state,
                                                    stateT);
    logits_kernel<<<dim3(125, 4), 256, 0, stream>>>(stateT, ow, ob, logits);
}